// Round 7
// baseline (492.651 us; speedup 1.0000x reference)
//
#include <hip/hip_runtime.h>
#include <cstdint>

// ---------------------------------------------------------------------------
// Problem constants
// ---------------------------------------------------------------------------
#define Bv   4
#define Nv   1024
#define Cv   1024
#define Hv   16
#define Iv   77
#define IDv  768
#define HDv  64
#define HIDv 4096
#define Sv   (Iv + Nv)      // 1101
#define BIv  (Bv * Iv)      // 308
#define BSv  (Bv * Sv)      // 4404
#define BNv  (Bv * Nv)      // 4096
#define SPADv 1152          // 18*64, zero-padded key dim for V^T

typedef __bf16 bf16x8_t __attribute__((ext_vector_type(8)));
typedef float  f32x4_t  __attribute__((ext_vector_type(4)));
typedef unsigned short us8_t __attribute__((ext_vector_type(8)));
typedef long  l2_t  __attribute__((ext_vector_type(2)));
typedef int   i32x4_t __attribute__((ext_vector_type(4)));
typedef int   i32x8_t __attribute__((ext_vector_type(8)));

__device__ inline f32x4_t zero4() { f32x4_t z; z[0]=0.f; z[1]=0.f; z[2]=0.f; z[3]=0.f; return z; }

// float -> bf16, round-nearest-even
__device__ inline unsigned short f2bf(float f) {
    unsigned int u = __builtin_bit_cast(unsigned int, f);
    u = (u + 0x7fffu + ((u >> 16) & 1u)) >> 16;
    return (unsigned short)u;
}
__device__ inline float bf2f(unsigned short u) {
    return __builtin_bit_cast(float, ((unsigned int)u) << 16);
}
// 4 floats -> packed fp8 e4m3 (HW convert, RNE sat)
__device__ inline unsigned int f4_fp8(float a, float b, float c, float d) {
    int v = __builtin_amdgcn_cvt_pk_fp8_f32(a, b, 0, false);
    v = __builtin_amdgcn_cvt_pk_fp8_f32(c, d, v, true);
    return (unsigned int)v;
}

// fast GELU (tanh approx via HW exp; max abs err ~1e-3, gamma-damped downstream)
__device__ inline float gelu_f(float x) {
    float u = 0.7978845608f * x * (1.0f + 0.044715f * x * x);
    float e = __expf(2.0f * u);
    float t = 1.0f - 2.0f / (e + 1.0f);
    return 0.5f * x * (1.0f + t);
}

// async global(16B/lane) -> LDS  (dest = wave-uniform base + lane*16)
__device__ inline void gload_lds16(const void* g, void* l) {
    __builtin_amdgcn_global_load_lds(
        (__attribute__((address_space(1))) void*)(unsigned long long)g,
        (__attribute__((address_space(3))) void*)(unsigned long long)l,
        16, 0, 0);
}

// two b128 reads (LDS or global) -> one 32B f8f6f4 operand fragment
__device__ inline i32x8_t frag32(const unsigned char* p0, const unsigned char* p1) {
    i32x4_t lo = *(const i32x4_t*)p0;
    i32x4_t hi = *(const i32x4_t*)p1;
    i32x8_t r;
    r[0] = lo[0]; r[1] = lo[1]; r[2] = lo[2]; r[3] = lo[3];
    r[4] = hi[0]; r[5] = hi[1]; r[6] = hi[2]; r[7] = hi[3];
    return r;
}

// ---------------------------------------------------------------------------
// Fused weight convert. fp8 x32 for qkv/proj/MLP; g1 NOT folded into proj
// (1e-5 would flush in fp8 — applied in proj_ln2). bf16 for ir1/ir2.
// order: qkv | proj | fc1 | fc2(*g2) | pfc1 | pfc2(*gate) | ir1 | ir2
// ---------------------------------------------------------------------------
__global__ __launch_bounds__(256) void cvt8_kernel(
        const float* s0, const float* s1, const float* s2, const float* s3,
        const float* s4, const float* s5, const float* s6, const float* s7,
        void* d0, void* d1, void* d2, void* d3,
        void* d4, void* d5, void* d6, void* d7,
        const float* g1, const float* g2, const float* gate) {
    (void)g1;
    long i = (long)blockIdx.x * 256 + threadIdx.x;
    const float* src; void* dst; long off;
    const float* sptr = nullptr; int K4 = 1; float wmul = 1.0f; bool f8 = false;
    if (i < 2097152) {
        if (i < 786432)       { src = s0; dst = d0; off = i; f8 = true; wmul = 32.f; }
        else if (i < 1048576) { src = s1; dst = d1; off = i - 786432;  f8 = true; wmul = 32.f; }
        else                  { src = s2; dst = d2; off = i - 1048576; f8 = true; wmul = 32.f; }
    } else if (i < 4194304) {
        if (i < 3145728)      { src = s3; dst = d3; off = i - 2097152; f8 = true; wmul = 32.f; sptr = g2; K4 = 1024; }
        else                  { src = s4; dst = d4; off = i - 3145728; f8 = true; wmul = 32.f; }
    } else {
        if (i < 5242880)      { src = s5; dst = d5; off = i - 4194304; f8 = true; wmul = 32.f; sptr = gate; K4 = 0x7fffffff; }
        else if (i < 5439488) { src = s6; dst = d6; off = i - 5242880; }
        else                  { src = s7; dst = d7; off = i - 5439488; }
    }
    float sc = (sptr ? sptr[(int)(off / K4)] : 1.0f) * wmul;
    float4 v = ((const float4*)src)[off];
    if (f8) {
        ((unsigned int*)dst)[off] = f4_fp8(v.x * sc, v.y * sc, v.z * sc, v.w * sc);
    } else {
        ushort4 o = {f2bf(v.x * sc), f2bf(v.y * sc), f2bf(v.z * sc), f2bf(v.w * sc)};
        ((ushort4*)dst)[off] = o;
    }
}

// qkvb=[qb,0,vb]; bfuse=g2*fc2b+gate*pfc2b; projb=g1*projb; bcat=[fc1b,pfc1b]
__global__ __launch_bounds__(256) void bias_prep_kernel(
        const float* __restrict__ qb, const float* __restrict__ vb,
        const float* __restrict__ fc2b, const float* __restrict__ pfc2b,
        const float* __restrict__ projb_in,
        const float* __restrict__ fc1b, const float* __restrict__ pfc1b,
        const float* __restrict__ g1, const float* __restrict__ g2,
        const float* __restrict__ gate,
        float* __restrict__ qkvb, float* __restrict__ bfuse,
        float* __restrict__ projb, float* __restrict__ bcat) {
    int i = blockIdx.x * 256 + threadIdx.x;
    if (i < 3 * Cv) {
        float v = 0.f;
        if (i < Cv) v = qb[i];
        else if (i >= 2 * Cv) v = vb[i - 2 * Cv];
        qkvb[i] = v;
    } else if (i < 4 * Cv) {
        int n = i - 3 * Cv;
        bfuse[n] = g2[n] * fc2b[n] + gate[0] * pfc2b[n];
    } else if (i < 5 * Cv) {
        int n = i - 4 * Cv;
        projb[n] = g1[n] * projb_in[n];
    } else if (i < 13 * Cv) {
        int j = i - 5 * Cv;
        bcat[j] = (j < HIDv) ? fc1b[j] : pfc1b[j - HIDv];
    }
}

// ---------------------------------------------------------------------------
// LayerNorm (fp32 in) -> bf16 (F8=0) or fp8(16*y) (F8=1), one row per block.
// out row index = (r/div)*stride + r%div + off
// ---------------------------------------------------------------------------
template <int F8>
__global__ __launch_bounds__(256) void ln_kernel(const float* __restrict__ in,
                                                 const float* __restrict__ w,
                                                 const float* __restrict__ bvec,
                                                 void* __restrict__ out,
                                                 int cols, float invcols,
                                                 int div_, int stride_, int off_) {
    const int r = blockIdx.x;
    const int tid = threadIdx.x;
    const float* row = in + (size_t)r * cols;
    float s = 0.f, s2 = 0.f;
    for (int c = tid * 4; c < cols; c += 1024) {
        float4 v = *(const float4*)(row + c);
        s  += v.x + v.y + v.z + v.w;
        s2 += v.x * v.x + v.y * v.y + v.z * v.z + v.w * v.w;
    }
#pragma unroll
    for (int o2 = 32; o2 > 0; o2 >>= 1) { s += __shfl_down(s, o2); s2 += __shfl_down(s2, o2); }
    __shared__ float sh[10];
    const int lane = tid & 63, wave = tid >> 6;
    if (lane == 0) { sh[wave] = s; sh[4 + wave] = s2; }
    __syncthreads();
    if (tid == 0) {
        float S1 = sh[0] + sh[1] + sh[2] + sh[3];
        float S2 = sh[4] + sh[5] + sh[6] + sh[7];
        float mean = S1 * invcols;
        float var  = S2 * invcols - mean * mean;
        sh[8] = mean;
        sh[9] = rsqrtf(var + 1e-5f);
    }
    __syncthreads();
    const float mean = sh[8], rstd = sh[9];
    const size_t orow = (size_t)((r / div_) * stride_ + (r % div_) + off_) * cols;
    for (int c = tid * 4; c < cols; c += 1024) {
        float4 v  = *(const float4*)(row + c);
        float4 wv = *(const float4*)(w + c);
        float4 bv = *(const float4*)(bvec + c);
        float o0 = (v.x - mean) * rstd * wv.x + bv.x;
        float o1 = (v.y - mean) * rstd * wv.y + bv.y;
        float o2 = (v.z - mean) * rstd * wv.z + bv.z;
        float o3 = (v.w - mean) * rstd * wv.w + bv.w;
        if constexpr (F8) {
            *(unsigned int*)((unsigned char*)out + orow + c) =
                f4_fp8(o0 * 16.f, o1 * 16.f, o2 * 16.f, o3 * 16.f);
        } else {
            ushort4 o = {f2bf(o0), f2bf(o1), f2bf(o2), f2bf(o3)};
            *(ushort4*)((unsigned short*)out + orow + c) = o;
        }
    }
}

// ---------------------------------------------------------------------------
// Fused proj-reduce + LayerNorm2: per row r,
//   x1 = x + projb + g1 * (parts0 + parts1);  write x1 (fp32)
//   y8 = fp8(16 * ((x1-mean)*rstd*w + b))
// ---------------------------------------------------------------------------
__global__ __launch_bounds__(256) void proj_ln2_kernel(
        const unsigned short* __restrict__ parts,
        const float* __restrict__ x,
        const float* __restrict__ projb,
        const float* __restrict__ g1,
        const float* __restrict__ w, const float* __restrict__ bvec,
        float* __restrict__ x1, unsigned char* __restrict__ y8) {
    const int r = blockIdx.x;
    const int tid = threadIdx.x;
    const int c = tid * 4;
    const size_t base = (size_t)r * Cv + c;
    float4 xv = *(const float4*)(x + base);
    float4 pb = *(const float4*)(projb + c);
    float4 gv = *(const float4*)(g1 + c);
    ushort4 u0 = *(const ushort4*)(parts + base);
    ushort4 u1 = *(const ushort4*)(parts + (size_t)BNv * Cv + base);
    float4 v;
    v.x = xv.x + pb.x + gv.x * (bf2f(u0.x) + bf2f(u1.x));
    v.y = xv.y + pb.y + gv.y * (bf2f(u0.y) + bf2f(u1.y));
    v.z = xv.z + pb.z + gv.z * (bf2f(u0.z) + bf2f(u1.z));
    v.w = xv.w + pb.w + gv.w * (bf2f(u0.w) + bf2f(u1.w));
    *(float4*)(x1 + base) = v;

    float s  = v.x + v.y + v.z + v.w;
    float s2 = v.x * v.x + v.y * v.y + v.z * v.z + v.w * v.w;
#pragma unroll
    for (int o2 = 32; o2 > 0; o2 >>= 1) { s += __shfl_down(s, o2); s2 += __shfl_down(s2, o2); }
    __shared__ float sh[10];
    const int lane = tid & 63, wave = tid >> 6;
    if (lane == 0) { sh[wave] = s; sh[4 + wave] = s2; }
    __syncthreads();
    if (tid == 0) {
        float S1 = sh[0] + sh[1] + sh[2] + sh[3];
        float S2 = sh[4] + sh[5] + sh[6] + sh[7];
        float mean = S1 * (1.0f / Cv);
        float var  = S2 * (1.0f / Cv) - mean * mean;
        sh[8] = mean;
        sh[9] = rsqrtf(var + 1e-5f);
    }
    __syncthreads();
    const float mean = sh[8], rstd = sh[9];
    float4 wv = *(const float4*)(w + c);
    float4 bv = *(const float4*)(bvec + c);
    float o0 = (v.x - mean) * rstd * wv.x + bv.x;
    float o1 = (v.y - mean) * rstd * wv.y + bv.y;
    float o2 = (v.z - mean) * rstd * wv.z + bv.z;
    float o3 = (v.w - mean) * rstd * wv.w + bv.w;
    *(unsigned int*)(y8 + base) = f4_fp8(o0 * 16.f, o1 * 16.f, o2 * 16.f, o3 * 16.f);
}

// ---------------------------------------------------------------------------
// Tiny-M bf16 GEMM: one 16x64 output tile per wave, operands read directly
// from global (ir-branch matrices are L2-resident). No LDS, no barriers.
// MODE 1: gelu -> bf16 at [r*N+cb]. MODE 2: fp8(16*v) scattered into cat
// rows (r/Iv)*Sv + r%Iv (byte stride Cv).
// ---------------------------------------------------------------------------
template <int MODE>
__global__ __launch_bounds__(256) void gemm_tiny_kernel(
        const unsigned short* __restrict__ A,
        const unsigned short* __restrict__ W,
        const float* __restrict__ bias,
        unsigned short* __restrict__ outp,
        int M, int N, int K) {
    const int lane = threadIdx.x & 63;
    const int wave = threadIdx.x >> 6;
    const int m16  = lane & 15;
    const int g4   = lane >> 4;
    const int wid  = blockIdx.x * 4 + wave;
    const int ntiles = N >> 6;
    const int mti = wid / ntiles;
    if (mti * 16 >= M + 15) return;
    const int m0 = mti * 16;
    const int n0 = (wid % ntiles) * 64;

    int am = m0 + m16; if (am > M - 1) am = M - 1;
    const unsigned short* ap = A + (size_t)am * K + g4 * 8;
    const unsigned short* wp = W + (size_t)(n0 + m16) * K + g4 * 8;

    f32x4_t acc[4];
#pragma unroll
    for (int a = 0; a < 4; ++a) acc[a] = zero4();

#pragma unroll 2
    for (int kk = 0; kk < K; kk += 32) {
        bf16x8_t xf = *(const bf16x8_t*)(ap + kk);
#pragma unroll
        for (int a = 0; a < 4; ++a) {
            bf16x8_t wf = *(const bf16x8_t*)(wp + (size_t)a * 16 * K + kk);
            acc[a] = __builtin_amdgcn_mfma_f32_16x16x32_bf16(wf, xf, acc[a], 0, 0, 0);
        }
    }

    const int r = m0 + m16;
    if (r >= M) return;
#pragma unroll
    for (int a = 0; a < 4; ++a) {
        const int cb = n0 + a * 16 + g4 * 4;
        const float4 bv4 = *(const float4*)(bias + cb);
        const float v0 = acc[a][0] + bv4.x;
        const float v1 = acc[a][1] + bv4.y;
        const float v2 = acc[a][2] + bv4.z;
        const float v3 = acc[a][3] + bv4.w;
        if constexpr (MODE == 1) {
            ushort4 o = {f2bf(gelu_f(v0)), f2bf(gelu_f(v1)),
                         f2bf(gelu_f(v2)), f2bf(gelu_f(v3))};
            *(ushort4*)(outp + (size_t)r * N + cb) = o;
        } else {
            const int rr2 = (r / Iv) * Sv + (r % Iv);
            *(unsigned int*)((unsigned char*)outp + (size_t)rr2 * Cv + cb) =
                f4_fp8(v0 * 16.f, v1 * 16.f, v2 * 16.f, v3 * 16.f);
        }
    }
}

// ---------------------------------------------------------------------------
// MX-fp8 GEMM (unit scales) -> bf16 out + bias. BK=128.
// B-ONLY LDS (32 KiB, XOR slot-swizzled) -> ~5 blocks/CU; A fragments loaded
// DIRECT from global (A is L2-resident: cat8 4.5 MB / ybuf8 4 MB). Lane's
// effective A bytes are [row, g4*32..+32) — identical math to the LDS path.
// M-clamped per-fragment A rows + guarded stores (qkv: M=4404).
// ---------------------------------------------------------------------------
__global__ __launch_bounds__(256) void gemm_fp8_bf16out_kernel(
        const unsigned char* __restrict__ A,
        const unsigned char* __restrict__ W,
        const float* __restrict__ bias,
        unsigned short* __restrict__ outp,
        int M, int N, int K) {
    __shared__ unsigned char Bs[2][128 * 128];
    const int tid  = threadIdx.x;
    const int lane = tid & 63;
    const int wave = tid >> 6;
    const int m16  = lane & 15;
    const int g4   = lane >> 4;
    const int n0 = blockIdx.x * 128;
    const int m0 = blockIdx.y * 128;
    const int wm = (wave >> 1) * 64;
    const int wn = (wave & 1) * 64;

    const int rowin = tid >> 3;                       // 0..31
    const int sslot = (tid & 7) ^ (rowin & 7);
    const unsigned char* bgp = W + (size_t)(n0 + rowin) * K + sslot * 16;

    // per-lane direct A pointers, one per fragment row
    const unsigned char* ap[4];
#pragma unroll
    for (int bb = 0; bb < 4; ++bb) {
        int gr = m0 + wm + bb * 16 + m16; if (gr > M - 1) gr = M - 1;
        ap[bb] = A + (size_t)gr * K + g4 * 32;
    }

    const int sw = m16 & 7;
    const int ra0 = ((2 * g4) ^ sw) * 16;
    const int ra1 = ((2 * g4 + 1) ^ sw) * 16;

    f32x4_t acc[4][4];
#pragma unroll
    for (int a = 0; a < 4; ++a)
#pragma unroll
        for (int bb = 0; bb < 4; ++bb) acc[a][bb] = zero4();

    auto stageB = [&](int buf) {
#pragma unroll
        for (int j = 0; j < 4; ++j)
            gload_lds16(bgp + (size_t)j * 32 * K, &Bs[buf][j * 4096 + wave * 1024]);
        bgp += 128;
    };

    stageB(0);
    const int NIT = K >> 7;
    for (int it = 0; it < NIT; ++it) {
        const int cur = it & 1;
        __syncthreads();
        if (it + 1 < NIT) stageB(cur ^ 1);
        i32x8_t xv[4], wv[4];
#pragma unroll
        for (int bb = 0; bb < 4; ++bb) {
            xv[bb] = frag32(ap[bb], ap[bb] + 16);
            ap[bb] += 128;
        }
#pragma unroll
        for (int a = 0; a < 4; ++a) {
            const unsigned char* rb = &Bs[cur][(wn + a * 16 + m16) * 128];
            wv[a] = frag32(rb + ra0, rb + ra1);
        }
#pragma unroll
        for (int a = 0; a < 4; ++a)
#pragma unroll
            for (int bb = 0; bb < 4; ++bb)
                acc[a][bb] = __builtin_amdgcn_mfma_scale_f32_16x16x128_f8f6f4(
                    wv[a], xv[bb], acc[a][bb], 0, 0, 0, 0x7f7f7f7f, 0, 0x7f7f7f7f);
    }

    const float ds = 1.0f / 512.0f;
#pragma unroll
    for (int a = 0; a < 4; ++a) {
        const int cb = n0 + wn + a * 16 + g4 * 4;
        const float4 bv4 = *(const float4*)(bias + cb);
#pragma unroll
        for (int bb = 0; bb < 4; ++bb) {
            const int r = m0 + wm + bb * 16 + m16;
            if (r < M) {
                const size_t idx = (size_t)r * N + cb;
                ushort4 o = {f2bf(acc[a][bb][0] * ds + bv4.x),
                             f2bf(acc[a][bb][1] * ds + bv4.y),
                             f2bf(acc[a][bb][2] * ds + bv4.z),
                             f2bf(acc[a][bb][3] * ds + bv4.w)};
                *(ushort4*)(outp + idx) = o;
            }
        }
    }
}

// ---------------------------------------------------------------------------
// MX-fp8 GEMM, BK=128, fused gelu epilogue (fc1+pfc1).
// B-ONLY LDS (32 KiB) + A-direct-from-global (ybuf8, L2-hot per XCD via the
// XCD-grouped m-tiles). ~5 blocks/CU vs 2 with dual-LDS.
// out fp8 = fp8( 16 * gelu(acc/512 + bias) ).  M must be multiple of 128.
// ---------------------------------------------------------------------------
__global__ __launch_bounds__(256) void gemm_fp8_gelu_kernel(
        const unsigned char* __restrict__ A,
        const unsigned char* __restrict__ W,
        const float* __restrict__ bias,
        unsigned char* __restrict__ outp,
        int M, int N, int K) {
    __shared__ unsigned char Bs[2][128 * 128];
    const int tid  = threadIdx.x;
    const int lane = tid & 63;
    const int wave = tid >> 6;
    const int m16  = lane & 15;
    const int g4   = lane >> 4;
    const int bid = blockIdx.x;
    const int xcd = bid & 7, l = bid >> 3;
    const int by = (xcd << 2) | (l & 3);   // m-tile (32)
    const int bx = l >> 2;                 // n-tile (64)
    const int n0 = bx * 128;
    const int m0 = by * 128;
    const int wm = (wave >> 1) * 64;
    const int wn = (wave & 1) * 64;

    const int rowin = tid >> 3;                       // 0..31
    const int sslot = (tid & 7) ^ (rowin & 7);
    const unsigned char* bgp = W + (size_t)(n0 + rowin) * K + sslot * 16;

    const unsigned char* ap[4];
#pragma unroll
    for (int bb = 0; bb < 4; ++bb)
        ap[bb] = A + (size_t)(m0 + wm + bb * 16 + m16) * K + g4 * 32;

    const int sw = m16 & 7;
    const int ra0 = ((2 * g4) ^ sw) * 16;
    const int ra1 = ((2 * g4 + 1) ^ sw) * 16;

    f32x4_t acc[4][4];
#pragma unroll
    for (int a = 0; a < 4; ++a)
#pragma unroll
        for (int bb = 0; bb < 4; ++bb) acc[a][bb] = zero4();

    auto stageB = [&](int buf) {
#pragma unroll
        for (int j = 0; j < 4; ++j)
            gload_lds16(bgp + (size_t)j * 32 * K, &Bs[buf][j * 4096 + wave * 1024]);
        bgp += 128;
    };

    stageB(0);
    const int NIT = K >> 7;
    for (int it = 0; it < NIT; ++it) {
        const int cur = it & 1;
        __syncthreads();
        if (it + 1 < NIT) stageB(cur ^ 1);
        i32x8_t xv[4], wv[4];
#pragma unroll
        for (int bb = 0; bb < 4; ++bb) {
            xv[bb] = frag32(ap[bb], ap[bb] + 16);
            ap[bb] += 128;
        }
#pragma unroll
        for (int a = 0; a < 4; ++a) {
            const unsigned char* rb = &Bs[cur][(wn + a * 16 + m16) * 128];
            wv[a] = frag32(rb + ra0, rb + ra1);
        }
#pragma unroll
        for (int a = 0; a < 4; ++a)
#pragma unroll
            for (int bb = 0; bb < 4; ++bb)
                acc[a][bb] = __builtin_amdgcn_mfma_scale_f32_16x16x128_f8f6f4(
                    wv[a], xv[bb], acc[a][bb], 0, 0, 0, 0x7f7f7f7f, 0, 0x7f7f7f7f);
    }

    const float ds = 1.0f / 512.0f;
#pragma unroll
    for (int a = 0; a < 4; ++a) {
        const int cb = n0 + wn + a * 16 + g4 * 4;
        const float4 bv4 = *(const float4*)(bias + cb);
#pragma unroll
        for (int bb = 0; bb < 4; ++bb) {
            const int r = m0 + wm + bb * 16 + m16;
            const size_t idx = (size_t)r * N + cb;
            unsigned int pk = f4_fp8(gelu_f(acc[a][bb][0] * ds + bv4.x) * 16.f,
                                     gelu_f(acc[a][bb][1] * ds + bv4.y) * 16.f,
                                     gelu_f(acc[a][bb][2] * ds + bv4.z) * 16.f,
                                     gelu_f(acc[a][bb][3] * ds + bv4.w) * 16.f);
            *(unsigned int*)(outp + idx) = pk;
        }
    }
}

// ---------------------------------------------------------------------------
// MX-fp8 split-K GEMM -> bf16 partials (acc/512). XCD-swizzled 1D grid (512).
// z<zsplit -> (A1,W1) else (A2,W2); k0=(z%zsplit)*Kc. Dual-LDS drain mainloop
// (kept: fc2's A = gbufA 33.6 MB is NOT L2-fit; also serves as node-speed
// control vs the restructured fc1).
// ---------------------------------------------------------------------------
__global__ __launch_bounds__(256) void gemm_fp8_splitk_kernel(
        const unsigned char* __restrict__ A1,
        const unsigned char* __restrict__ W1,
        const unsigned char* __restrict__ A2,
        const unsigned char* __restrict__ W2,
        unsigned short* __restrict__ parts,
        int M, int N, int lda, int ldw, int Kc, int zsplit) {
    __shared__ unsigned char As[2][128 * 128];
    __shared__ unsigned char Bs[2][128 * 128];
    const int tid  = threadIdx.x;
    const int lane = tid & 63;
    const int wave = tid >> 6;
    const int m16  = lane & 15;
    const int g4   = lane >> 4;
    const int bid = blockIdx.x;
    const int xcd = bid & 7, l = bid >> 3;
    const int by = (xcd << 2) | (l & 3);
    const int rr = l >> 2;
    const int bx = rr & 7;
    const int z  = rr >> 3;
    const int n0 = bx * 128;
    const int m0 = by * 128;
    const int wm = (wave >> 1) * 64;
    const int wn = (wave & 1) * 64;

    const unsigned char* A = (z < zsplit) ? A1 : A2;
    const unsigned char* W = (z < zsplit) ? W1 : W2;
    const int k0 = (z % zsplit) * Kc;

    const int rowin = tid >> 3;
    const int sslot = (tid & 7) ^ (rowin & 7);
    const unsigned char* agp = A + (size_t)(m0 + rowin) * lda + k0 + sslot * 16;
    const unsigned char* bgp = W + (size_t)(n0 + rowin) * ldw + k0 + sslot * 16;

    const int sw = m16 & 7;
    const int ra0 = ((2 * g4) ^ sw) * 16;
    const int ra1 = ((2 * g4 + 1) ^ sw) * 16;

    f32x4_t acc[4][4];
#pragma unroll
    for (int a = 0; a < 4; ++a)
#pragma unroll
        for (int bb = 0; bb < 4; ++bb) acc[a][bb] = zero4();

    auto stage = [&](int buf) {
#pragma unroll
        for (int j = 0; j < 4; ++j) {
            gload_lds16(agp + (size_t)j * 32 * lda, &As[buf][j * 4096 + wave * 1024]);
            gload_lds16(bgp + (size_t)j * 32 * ldw, &Bs[buf][j * 4096 + wave * 1024]);
        }
        agp += 128; bgp += 128;
    };

    stage(0);
    const int NIT = Kc >> 7;
    for (int it = 0; it < NIT; ++it) {
        const int cur = it & 1;
        __syncthreads();
        if (it + 1 < NIT) stage(cur ^ 1);
        i32x8_t xv[4], wv[4];
#pragma unroll
        for (int bb = 0; bb < 4; ++bb) {
            const unsigned char* rb = &As[cur][(wm + bb * 16 + m16) * 128];
            xv[bb] = frag32(rb + ra0, rb + ra1);
        }
#pragma unroll
        for (int a = 0; a < 4; ++a) {
            const unsigned char* rb = &Bs[cur][(wn + a * 16 + m16) * 128];
            wv[a] = frag32(rb + ra0, rb + ra1);
        }
#pragma unroll
        for (int a = 0; a < 4; ++a)
#pragma unroll
            for (int bb = 0; bb < 4; ++bb)
                acc[a][bb] = __builtin_amdgcn_mfma_scale_f32_16x16x128_f8f6f4(
                    wv[a], xv[bb], acc[a][bb], 0, 0, 0, 0x7f7f7f7f, 0, 0x7f7f7f7f);
    }

    unsigned short* pz = parts + (size_t)z * M * N;
    const float ds = 1.0f / 512.0f;
#pragma unroll
    for (int a = 0; a < 4; ++a) {
        const int cb = n0 + wn + a * 16 + g4 * 4;
#pragma unroll
        for (int bb = 0; bb < 4; ++bb) {
            const int r = m0 + wm + bb * 16 + m16;
            const size_t idx = (size_t)r * N + cb;
            ushort4 o = {f2bf(acc[a][bb][0] * ds), f2bf(acc[a][bb][1] * ds),
                         f2bf(acc[a][bb][2] * ds), f2bf(acc[a][bb][3] * ds)};
            *(ushort4*)(pz + idx) = o;
        }
    }
}

// ---------------------------------------------------------------------------
// Split-K reduce: out[i] = resid[i] + bias[i%N] + sum_z parts[z][i]  (fp32 out)
// ---------------------------------------------------------------------------
template <int NP>
__global__ __launch_bounds__(256) void reduce_kernel(
        const unsigned short* __restrict__ parts,
        const float* __restrict__ resid,
        const float* __restrict__ bias,
        float* __restrict__ out, int MN, int N4mask) {
    int i = blockIdx.x * 256 + threadIdx.x;
    if (i * 4 >= MN) return;
    float4 res = ((const float4*)resid)[i];
    float4 bv  = *(const float4*)(bias + (i & N4mask) * 4);
    float4 o = {res.x + bv.x, res.y + bv.y, res.z + bv.z, res.w + bv.w};
#pragma unroll
    for (int z = 0; z < NP; ++z) {
        ushort4 u = ((const ushort4*)(parts + (size_t)z * MN))[i];
        o.x += bf2f(u.x); o.y += bf2f(u.y); o.z += bf2f(u.z); o.w += bf2f(u.w);
    }
    ((float4*)out)[i] = o;
}

// ---------------------------------------------------------------------------
// V^T pre-transpose with baked PV key-permutation.
// ---------------------------------------------------------------------------
__global__ __launch_bounds__(256) void vtrans_kernel(const unsigned short* __restrict__ qkv,
                                                     unsigned short* __restrict__ vt) {
    __shared__ unsigned short Vs[64 * 64];
    const int stile = blockIdx.x;
    const int bh = blockIdx.y;
    const int b = bh >> 4, h = bh & 15;
    const int tid = threadIdx.x;
#pragma unroll
    for (int j = 0; j < 2; ++j) {
        int c = j * 256 + tid;
        int r = c >> 3, d8 = (c & 7) * 8;
        int s = stile * 64 + r;
        uint4 v = {0u, 0u, 0u, 0u};
        if (s < Sv) v = *(const uint4*)(qkv + ((size_t)(b * Sv + s) * 3 + 2) * Cv + h * 64 + d8);
        *(uint4*)&Vs[r * 64 + d8] = v;
    }
    __syncthreads();
    const int d  = tid >> 2;
    const int p0 = (tid & 3) * 16;
    unsigned short tmp[16];
#pragma unroll
    for (int e = 0; e < 16; ++e) {
        int p = p0 + e;
        int s_local = (p & 32) + 16 * ((p >> 2) & 1) + 4 * ((p & 31) >> 3) + (p & 3);
        tmp[e] = Vs[s_local * 64 + d];
    }
    unsigned short* dst = vt + ((size_t)bh * 64 + d) * SPADv + stile * 64 + p0;
    *(uint4*)dst       = *(const uint4*)&tmp[0];
    *(uint4*)(dst + 8) = *(const uint4*)&tmp[8];
}

// ---------------------------------------------------------------------------
// Flash attention, S^T formulation. Output -> fp8(16*o) for fp8 proj.
// (setprio removed: lockstep 4-wave blocks = documented null/negative regime.)
// ---------------------------------------------------------------------------
__global__ __launch_bounds__(256) void attn_kernel(const unsigned short* __restrict__ qkv,
                                                   const unsigned short* __restrict__ vt,
                                                   unsigned char* __restrict__ o) {
    __shared__ unsigned short Qs[64 * 64];
    __shared__ unsigned short Ks[2][64 * 64];
    __shared__ unsigned short Vts[2][64 * 64];

    const int tid  = threadIdx.x;
    const int lane = tid & 63;
    const int wave = tid >> 6;
    const int m16  = lane & 15;
    const int g4   = lane >> 4;
    const int qt = blockIdx.x;
    const int bh = blockIdx.y;
    const int b = bh >> 4, h = bh & 15;

    const int lr = lane >> 3;
    const int csw = ((lane & 7) ^ lr) * 8;
    const int sw7 = m16 & 7;

#pragma unroll
    for (int j = 0; j < 2; ++j) {
        int r = wave * 16 + j * 8 + lr;
        int s = Iv + qt * 64 + r;
        gload_lds16(qkv + ((size_t)(b * Sv + s) * 3) * Cv + h * 64 + csw,
                    &Qs[(wave * 16 + j * 8) * 64]);
    }

    auto stage_kv = [&](int st, int buf) {
#pragma unroll
        for (int j = 0; j < 2; ++j) {
            int r = wave * 16 + j * 8 + lr;
            int s = st * 64 + r; if (s > Sv - 1) s = Sv - 1;
            gload_lds16(qkv + ((size_t)(b * Sv + s) * 3 + 1) * Cv + h * 64 + csw,
                        &Ks[buf][(wave * 16 + j * 8) * 64]);
            gload_lds16(vt + ((size_t)bh * 64 + r) * SPADv + st * 64 + csw,
                        &Vts[buf][(wave * 16 + j * 8) * 64]);
        }
    };

    f32x4_t oacc[4];
#pragma unroll
    for (int dt = 0; dt < 4; ++dt) oacc[dt] = zero4();
    float m_run = -1e30f, l_run = 0.f;

    stage_kv(0, 0);
    __syncthreads();

    const bf16x8_t qf0 = *(const bf16x8_t*)&Qs[(wave * 16 + m16) * 64 + ((g4 ^ sw7) * 8)];
    const bf16x8_t qf1 = *(const bf16x8_t*)&Qs[(wave * 16 + m16) * 64 + (((4 + g4) ^ sw7) * 8)];

    const int NT = (Sv + 63) / 64;   // 18
    for (int st = 0; st < NT; ++st) {
        const int cur = st & 1;
        if (st + 1 < NT) stage_kv(st + 1, cur ^ 1);

        f32x4_t sc[4];
#pragma unroll
        for (int kt = 0; kt < 4; ++kt) {
            bf16x8_t k0 = *(const bf16x8_t*)&Ks[cur][(kt * 16 + m16) * 64 + ((g4 ^ sw7) * 8)];
            bf16x8_t k1 = *(const bf16x8_t*)&Ks[cur][(kt * 16 + m16) * 64 + (((4 + g4) ^ sw7) * 8)];
            f32x4_t z = zero4();
            z = __builtin_amdgcn_mfma_f32_16x16x32_bf16(k0, qf0, z, 0, 0, 0);
            z = __builtin_amdgcn_mfma_f32_16x16x32_bf16(k1, qf1, z, 0, 0, 0);
            sc[kt] = z;
        }

        float mx = -1e30f;
#pragma unroll
        for (int kt = 0; kt < 4; ++kt)
#pragma unroll
            for (int r = 0; r < 4; ++r) {
                int key = st * 64 + kt * 16 + g4 * 4 + r;
                float v = sc[kt][r] * 0.125f;
                v = (key < Sv) ? v : -1e30f;
                sc[kt][r] = v;
                mx = fmaxf(mx, v);
            }
        mx = fmaxf(mx, __shfl_xor(mx, 16));
        mx = fmaxf(mx, __shfl_xor(mx, 32));
        const float mnew  = fmaxf(m_run, mx);
        const float alpha = __expf(m_run - mnew);
        m_run = mnew;
        float sum = 0.f;
#pragma unroll
        for (int kt = 0; kt < 4; ++kt)
#pragma unroll
            for (int r = 0; r < 4; ++r) {
                float p = __expf(sc[kt][r] - mnew);
                sc[kt][r] = p;
                sum += p;
            }
        sum += __shfl_xor(sum, 16);
        sum += __shfl_xor(sum, 32);
        l_run = l_run * alpha + sum;
#pragma unroll
        for (int dt = 0; dt < 4; ++dt) oacc[dt] *= alpha;

        us8_t pu0, pu1;
#pragma unroll
        for (int j = 0; j < 8; ++j) {
            pu0[j] = f2bf(sc[(j >> 2)][j & 3]);
            pu1[j] = f2bf(sc[2 + (j >> 2)][j & 3]);
        }
        const bf16x8_t pf0 = __builtin_bit_cast(bf16x8_t, pu0);
        const bf16x8_t pf1 = __builtin_bit_cast(bf16x8_t, pu1);

#pragma unroll
        for (int dt = 0; dt < 4; ++dt) {
            bf16x8_t v0 = *(const bf16x8_t*)&Vts[cur][(dt * 16 + m16) * 64 + ((g4 ^ sw7) * 8)];
            bf16x8_t v1 = *(const bf16x8_t*)&Vts[cur][(dt * 16 + m16) * 64 + (((4 + g4) ^ sw7) * 8)];
            oacc[dt] = __builtin_amdgcn_mfma_f32_16x16x32_bf16(v0, pf0, oacc[dt], 0, 0, 0);
            oacc[dt] = __builtin_amdgcn_mfma_f32_16x16x32_bf16(v1, pf1, oacc[dt], 0, 0, 0);
        }
        __syncthreads();
    }

    const float inv16 = 16.0f / l_run;
    const int q = qt * 64 + wave * 16 + m16;
    const size_t row = (size_t)(b * Nv + q) * Cv + h * 64;
#pragma unroll
    for (int dt = 0; dt < 4; ++dt) {
        *(unsigned int*)&o[row + dt * 16 + g4 * 4] =
            f4_fp8(oacc[dt][0] * inv16, oacc[dt][1] * inv16,
                   oacc[dt][2] * inv16, oacc[dt][3] * inv16);
    }
}

// ---------------------------------------------------------------------------
// Launcher
// ---------------------------------------------------------------------------
extern "C" void kernel_launch(void* const* d_in, const int* in_sizes, int n_in,
                              void* d_out, int out_size, void* d_ws, size_t ws_size,
                              hipStream_t stream) {
    (void)in_sizes; (void)n_in; (void)out_size; (void)ws_size;
    const float* x       = (const float*)d_in[0];
    const float* instr   = (const float*)d_in[1];
    const float* norm1_w = (const float*)d_in[2];
    const float* norm1_b = (const float*)d_in[3];
    const float* qkv_w   = (const float*)d_in[4];
    const float* q_bias  = (const float*)d_in[5];
    const float* v_bias  = (const float*)d_in[6];
    const float* proj_w  = (const float*)d_in[7];
    const float* proj_b  = (const float*)d_in[8];
    const float* gamma_1 = (const float*)d_in[9];
    const float* gamma_2 = (const float*)d_in[10];
    const float* norm2_w = (const float*)d_in[11];
    const float* norm2_b = (const float*)d_in[12];
    const float* fc1_w   = (const float*)d_in[13];
    const float* fc1_b   = (const float*)d_in[14];
    const float* fc2_w   = (const float*)d_in[15];
    const float* fc2_b   = (const float*)d_in[16];
    const float* pfc1_w  = (const float*)d_in[17];
    const float* pfc1_b  = (const float*)d_in[18];
    const float* pfc2_w  = (const float*)d_in[19];
    const float* pfc2_b  = (const float*)d_in[20];
    const float* gate    = (const float*)d_in[21];
    const float* ir_ln_w = (const float*)d_in[22];
    const float* ir_ln_b = (const float*)d_in[23];
    const float* ir_l1_w = (const float*)d_in[24];
    const float* ir_l1_b = (const float*)d_in[25];
    const float* ir_l2_w = (const float*)d_in[26];
    const float* ir_l2_b = (const float*)d_in[27];
    float* out = (float*)d_out;

    char* ws = (char*)d_ws;
    size_t off = 0;
    auto alloc = [&](size_t bytes) -> char* {
        char* p = ws + off;
        off += (bytes + 255) & ~(size_t)255;
        return p;
    };
    unsigned char*  w_qkv8 = (unsigned char*)alloc((size_t)3 * Cv * Cv);       // fp8 x32
    unsigned char*  w_proj8= (unsigned char*)alloc((size_t)Cv * Cv);           // fp8 x32 (no g1)
    unsigned char*  w_mlp1 = (unsigned char*)alloc((size_t)2 * HIDv * Cv);     // fp8: fc1|pfc1 x32
    unsigned char*  w_fc2  = (unsigned char*)alloc((size_t)Cv * HIDv);         // fp8 *g2*32
    unsigned char*  w_pfc2 = (unsigned char*)alloc((size_t)Cv * HIDv);         // fp8 *gate*32
    unsigned short* w_ir1  = (unsigned short*)alloc((size_t)Cv * IDv * 2);
    unsigned short* w_ir2  = (unsigned short*)alloc((size_t)Cv * Cv * 2);
    float*          qkvb   = (float*)alloc((size_t)3 * Cv * 4);
    float*          bfuse  = (float*)alloc((size_t)Cv * 4);
    float*          projb  = (float*)alloc((size_t)Cv * 4);
    float*          bcat   = (float*)alloc((size_t)2 * HIDv * 4);
    unsigned short* irln   = (unsigned short*)alloc((size_t)BIv * IDv * 2);
    unsigned short* h1     = (unsigned short*)alloc((size_t)BIv * Cv * 2);
    unsigned char*  cat8   = (unsigned char*)alloc((size_t)BSv * Cv);          // fp8 x16, 4.5 MB
    unsigned short* qkvbuf = (unsigned short*)alloc((size_t)BSv * 3 * Cv * 2); // bf16 27.1 MB
    unsigned char*  obuf8  = (unsigned char*)alloc((size_t)BNv * Cv);          // fp8 x16
    float*          x1     = (float*)alloc((size_t)BNv * Cv * 4);
    unsigned char*  ybuf8  = (unsigned char*)alloc((size_t)BNv * Cv);          // fp8 x16
    unsigned char*  gbufA  = (unsigned char*)alloc((size_t)BNv * 2 * HIDv);    // fp8 33.6 MB
    unsigned short* fpart  = (unsigned short*)alloc((size_t)2 * BNv * Cv * 2); // 16.8 MB (2 partials)
    unsigned short* vt     = (unsigned short*)gbufA;  // vt dead before fc1 writes gbufA
    unsigned short* ppart  = fpart;                   // fpart free until fc2 splitk

    cvt8_kernel<<<22272, 256, 0, stream>>>(qkv_w, proj_w, fc1_w, fc2_w, pfc1_w, pfc2_w,
                                           ir_l1_w, ir_l2_w,
                                           w_qkv8, w_proj8, w_mlp1, w_fc2,
                                           w_mlp1 + (size_t)HIDv * Cv, w_pfc2,
                                           w_ir1, w_ir2,
                                           gamma_1, gamma_2, gate);

    bias_prep_kernel<<<52, 256, 0, stream>>>(q_bias, v_bias, fc2_b, pfc2_b, proj_b,
                                             fc1_b, pfc1_b,
                                             gamma_1, gamma_2, gate,
                                             qkvb, bfuse, projb, bcat);

    // instruct branch: LN -> Linear+GELU -> Linear (wave-tile GEMMs, no LDS)
    ln_kernel<0><<<BIv, 256, 0, stream>>>(instr, ir_ln_w, ir_ln_b, irln,
                                          IDv, 1.0f / IDv, 1 << 28, 0, 0);
    // LN1 writes fp8(16*y) directly into cat rows b*S + I + n
    ln_kernel<1><<<BNv, 256, 0, stream>>>(x, norm1_w, norm1_b, cat8,
                                          Cv, 1.0f / Cv, Nv, Sv, Iv);
    {
        const int wtiles = ((BIv + 15) / 16) * (Cv / 64);   // 20*16 = 320
        gemm_tiny_kernel<1><<<(wtiles + 3) / 4, 256, 0, stream>>>(
            irln, w_ir1, ir_l1_b, h1, BIv, Cv, IDv);
        gemm_tiny_kernel<2><<<(wtiles + 3) / 4, 256, 0, stream>>>(
            h1, w_ir2, ir_l2_b, (unsigned short*)cat8, BIv, Cv, Cv);
    }

    // QKV projection over cat [BS, C] fp8 -> [BS, 3C] bf16 (B-LDS + A-direct)
    gemm_fp8_bf16out_kernel<<<dim3(3 * Cv / 128, (BSv + 127) / 128), 256, 0, stream>>>(
        cat8, w_qkv8, qkvb, qkvbuf, BSv, 3 * Cv, Cv);

    // V^T pre-transpose (permuted), then attention (obuf fp8 x16)
    vtrans_kernel<<<dim3(18, Bv * Hv), 256, 0, stream>>>(qkvbuf, vt);
    attn_kernel<<<dim3(Nv / 64, Bv * Hv), 256, 0, stream>>>(qkvbuf, vt, obuf8);

    // proj MX-fp8 split-K=2 (Kc=512, NIT=4, 512 blocks = one full round)
    gemm_fp8_splitk_kernel<<<512, 256, 0, stream>>>(
        obuf8, w_proj8, obuf8, w_proj8, ppart,
        BNv, Cv, Cv, Cv, Cv / 2, 2);
    // fused: x1 = x + g1*proj_b + g1*sum(parts); LN2 -> fp8(16*y)
    proj_ln2_kernel<<<BNv, 256, 0, stream>>>(
        ppart, x, projb, gamma_1, norm2_w, norm2_b, x1, ybuf8);

    // fused fc1+pfc1 (B-LDS + A-direct, N=8192, XCD-swizzled 2048 blocks)
    gemm_fp8_gelu_kernel<<<2048, 256, 0, stream>>>(
        ybuf8, w_mlp1, bcat, gbufA, BNv, 2 * HIDv, Cv);

    // fc2 + pfc2 MX-fp8 split-K: z=0 -> fc2 (full K=4096), z=1 -> pfc2
    gemm_fp8_splitk_kernel<<<512, 256, 0, stream>>>(
        gbufA, w_fc2, gbufA + HIDv, w_pfc2, fpart,
        BNv, Cv, 2 * HIDv, HIDv, HIDv, 1);
    // out = x1 + (g2*fc2_b + gate*pfc2_b) + sum(parts)
    reduce_kernel<2><<<(BNv * Cv / 4 + 255) / 256, 256, 0, stream>>>(
        fpart, x1, bfuse, out, BNv * Cv, Cv / 4 - 1);
}

// Round 8
// 432.191 us; speedup vs baseline: 1.1399x; 1.1399x over previous
//
#include <hip/hip_runtime.h>
#include <cstdint>

// ---------------------------------------------------------------------------
// Problem constants
// ---------------------------------------------------------------------------
#define Bv   4
#define Nv   1024
#define Cv   1024
#define Hv   16
#define Iv   77
#define IDv  768
#define HDv  64
#define HIDv 4096
#define Sv   (Iv + Nv)      // 1101
#define BIv  (Bv * Iv)      // 308
#define BSv  (Bv * Sv)      // 4404
#define BNv  (Bv * Nv)      // 4096
#define SPADv 1152          // 18*64, zero-padded key dim for V^T

typedef __bf16 bf16x8_t __attribute__((ext_vector_type(8)));
typedef float  f32x4_t  __attribute__((ext_vector_type(4)));
typedef unsigned short us8_t __attribute__((ext_vector_type(8)));
typedef long  l2_t  __attribute__((ext_vector_type(2)));
typedef int   i32x4_t __attribute__((ext_vector_type(4)));
typedef int   i32x8_t __attribute__((ext_vector_type(8)));

__device__ inline f32x4_t zero4() { f32x4_t z; z[0]=0.f; z[1]=0.f; z[2]=0.f; z[3]=0.f; return z; }

// float -> bf16, round-nearest-even
__device__ inline unsigned short f2bf(float f) {
    unsigned int u = __builtin_bit_cast(unsigned int, f);
    u = (u + 0x7fffu + ((u >> 16) & 1u)) >> 16;
    return (unsigned short)u;
}
__device__ inline float bf2f(unsigned short u) {
    return __builtin_bit_cast(float, ((unsigned int)u) << 16);
}
// 4 floats -> packed fp8 e4m3 (HW convert, RNE sat)
__device__ inline unsigned int f4_fp8(float a, float b, float c, float d) {
    int v = __builtin_amdgcn_cvt_pk_fp8_f32(a, b, 0, false);
    v = __builtin_amdgcn_cvt_pk_fp8_f32(c, d, v, true);
    return (unsigned int)v;
}

// fast GELU (tanh approx via HW exp; max abs err ~1e-3, gamma-damped downstream)
__device__ inline float gelu_f(float x) {
    float u = 0.7978845608f * x * (1.0f + 0.044715f * x * x);
    float e = __expf(2.0f * u);
    float t = 1.0f - 2.0f / (e + 1.0f);
    return 0.5f * x * (1.0f + t);
}

// async global(16B/lane) -> LDS  (dest = wave-uniform base + lane*16)
__device__ inline void gload_lds16(const void* g, void* l) {
    __builtin_amdgcn_global_load_lds(
        (__attribute__((address_space(1))) void*)(unsigned long long)g,
        (__attribute__((address_space(3))) void*)(unsigned long long)l,
        16, 0, 0);
}

// two swizzled b128 LDS reads -> one 32B f8f6f4 operand fragment
__device__ inline i32x8_t frag32(const unsigned char* p0, const unsigned char* p1) {
    i32x4_t lo = *(const i32x4_t*)p0;
    i32x4_t hi = *(const i32x4_t*)p1;
    i32x8_t r;
    r[0] = lo[0]; r[1] = lo[1]; r[2] = lo[2]; r[3] = lo[3];
    r[4] = hi[0]; r[5] = hi[1]; r[6] = hi[2]; r[7] = hi[3];
    return r;
}

// counted-vmcnt wait + raw barrier (T4) — small bf16 GEMMs only.
#define PIPE_WAIT(N) do { \
    asm volatile("s_waitcnt vmcnt(" #N ")" ::: "memory"); \
    __builtin_amdgcn_s_barrier(); \
    __builtin_amdgcn_sched_barrier(0); \
} while (0)
#define PIPE_RELEASE() do { \
    __builtin_amdgcn_sched_barrier(0); \
    __builtin_amdgcn_s_barrier(); \
} while (0)

// ---------------------------------------------------------------------------
// Fused weight convert. fp8 x32 for qkv/proj/MLP; g1 NOT folded into proj
// (1e-5 would flush in fp8 — applied in proj_ln2). bf16 for ir1/ir2.
// order: qkv | proj | fc1 | fc2(*g2) | pfc1 | pfc2(*gate) | ir1 | ir2
// ---------------------------------------------------------------------------
__global__ __launch_bounds__(256) void cvt8_kernel(
        const float* s0, const float* s1, const float* s2, const float* s3,
        const float* s4, const float* s5, const float* s6, const float* s7,
        void* d0, void* d1, void* d2, void* d3,
        void* d4, void* d5, void* d6, void* d7,
        const float* g1, const float* g2, const float* gate) {
    (void)g1;
    long i = (long)blockIdx.x * 256 + threadIdx.x;
    const float* src; void* dst; long off;
    const float* sptr = nullptr; int K4 = 1; float wmul = 1.0f; bool f8 = false;
    if (i < 2097152) {
        if (i < 786432)       { src = s0; dst = d0; off = i; f8 = true; wmul = 32.f; }
        else if (i < 1048576) { src = s1; dst = d1; off = i - 786432;  f8 = true; wmul = 32.f; }
        else                  { src = s2; dst = d2; off = i - 1048576; f8 = true; wmul = 32.f; }
    } else if (i < 4194304) {
        if (i < 3145728)      { src = s3; dst = d3; off = i - 2097152; f8 = true; wmul = 32.f; sptr = g2; K4 = 1024; }
        else                  { src = s4; dst = d4; off = i - 3145728; f8 = true; wmul = 32.f; }
    } else {
        if (i < 5242880)      { src = s5; dst = d5; off = i - 4194304; f8 = true; wmul = 32.f; sptr = gate; K4 = 0x7fffffff; }
        else if (i < 5439488) { src = s6; dst = d6; off = i - 5242880; }
        else                  { src = s7; dst = d7; off = i - 5439488; }
    }
    float sc = (sptr ? sptr[(int)(off / K4)] : 1.0f) * wmul;
    float4 v = ((const float4*)src)[off];
    if (f8) {
        ((unsigned int*)dst)[off] = f4_fp8(v.x * sc, v.y * sc, v.z * sc, v.w * sc);
    } else {
        ushort4 o = {f2bf(v.x * sc), f2bf(v.y * sc), f2bf(v.z * sc), f2bf(v.w * sc)};
        ((ushort4*)dst)[off] = o;
    }
}

// qkvb=[qb,0,vb]; bfuse=g2*fc2b+gate*pfc2b; projb=g1*projb; bcat=[fc1b,pfc1b]
__global__ __launch_bounds__(256) void bias_prep_kernel(
        const float* __restrict__ qb, const float* __restrict__ vb,
        const float* __restrict__ fc2b, const float* __restrict__ pfc2b,
        const float* __restrict__ projb_in,
        const float* __restrict__ fc1b, const float* __restrict__ pfc1b,
        const float* __restrict__ g1, const float* __restrict__ g2,
        const float* __restrict__ gate,
        float* __restrict__ qkvb, float* __restrict__ bfuse,
        float* __restrict__ projb, float* __restrict__ bcat) {
    int i = blockIdx.x * 256 + threadIdx.x;
    if (i < 3 * Cv) {
        float v = 0.f;
        if (i < Cv) v = qb[i];
        else if (i >= 2 * Cv) v = vb[i - 2 * Cv];
        qkvb[i] = v;
    } else if (i < 4 * Cv) {
        int n = i - 3 * Cv;
        bfuse[n] = g2[n] * fc2b[n] + gate[0] * pfc2b[n];
    } else if (i < 5 * Cv) {
        int n = i - 4 * Cv;
        projb[n] = g1[n] * projb_in[n];
    } else if (i < 13 * Cv) {
        int j = i - 5 * Cv;
        bcat[j] = (j < HIDv) ? fc1b[j] : pfc1b[j - HIDv];
    }
}

// ---------------------------------------------------------------------------
// LayerNorm (fp32 in) -> bf16 (F8=0) or fp8(16*y) (F8=1), one row per block.
// out row index = (r/div)*stride + r%div + off
// ---------------------------------------------------------------------------
template <int F8>
__global__ __launch_bounds__(256) void ln_kernel(const float* __restrict__ in,
                                                 const float* __restrict__ w,
                                                 const float* __restrict__ bvec,
                                                 void* __restrict__ out,
                                                 int cols, float invcols,
                                                 int div_, int stride_, int off_) {
    const int r = blockIdx.x;
    const int tid = threadIdx.x;
    const float* row = in + (size_t)r * cols;
    float s = 0.f, s2 = 0.f;
    for (int c = tid * 4; c < cols; c += 1024) {
        float4 v = *(const float4*)(row + c);
        s  += v.x + v.y + v.z + v.w;
        s2 += v.x * v.x + v.y * v.y + v.z * v.z + v.w * v.w;
    }
#pragma unroll
    for (int o2 = 32; o2 > 0; o2 >>= 1) { s += __shfl_down(s, o2); s2 += __shfl_down(s2, o2); }
    __shared__ float sh[10];
    const int lane = tid & 63, wave = tid >> 6;
    if (lane == 0) { sh[wave] = s; sh[4 + wave] = s2; }
    __syncthreads();
    if (tid == 0) {
        float S1 = sh[0] + sh[1] + sh[2] + sh[3];
        float S2 = sh[4] + sh[5] + sh[6] + sh[7];
        float mean = S1 * invcols;
        float var  = S2 * invcols - mean * mean;
        sh[8] = mean;
        sh[9] = rsqrtf(var + 1e-5f);
    }
    __syncthreads();
    const float mean = sh[8], rstd = sh[9];
    const size_t orow = (size_t)((r / div_) * stride_ + (r % div_) + off_) * cols;
    for (int c = tid * 4; c < cols; c += 1024) {
        float4 v  = *(const float4*)(row + c);
        float4 wv = *(const float4*)(w + c);
        float4 bv = *(const float4*)(bvec + c);
        float o0 = (v.x - mean) * rstd * wv.x + bv.x;
        float o1 = (v.y - mean) * rstd * wv.y + bv.y;
        float o2 = (v.z - mean) * rstd * wv.z + bv.z;
        float o3 = (v.w - mean) * rstd * wv.w + bv.w;
        if constexpr (F8) {
            *(unsigned int*)((unsigned char*)out + orow + c) =
                f4_fp8(o0 * 16.f, o1 * 16.f, o2 * 16.f, o3 * 16.f);
        } else {
            ushort4 o = {f2bf(o0), f2bf(o1), f2bf(o2), f2bf(o3)};
            *(ushort4*)((unsigned short*)out + orow + c) = o;
        }
    }
}

// ---------------------------------------------------------------------------
// Fused proj-reduce + LayerNorm2: per row r,
//   x1 = x + projb + g1 * (parts0 + parts1);  write x1 (fp32)
//   y8 = fp8(16 * ((x1-mean)*rstd*w + b))
// ---------------------------------------------------------------------------
__global__ __launch_bounds__(256) void proj_ln2_kernel(
        const unsigned short* __restrict__ parts,
        const float* __restrict__ x,
        const float* __restrict__ projb,
        const float* __restrict__ g1,
        const float* __restrict__ w, const float* __restrict__ bvec,
        float* __restrict__ x1, unsigned char* __restrict__ y8) {
    const int r = blockIdx.x;
    const int tid = threadIdx.x;
    const int c = tid * 4;
    const size_t base = (size_t)r * Cv + c;
    float4 xv = *(const float4*)(x + base);
    float4 pb = *(const float4*)(projb + c);
    float4 gv = *(const float4*)(g1 + c);
    ushort4 u0 = *(const ushort4*)(parts + base);
    ushort4 u1 = *(const ushort4*)(parts + (size_t)BNv * Cv + base);
    float4 v;
    v.x = xv.x + pb.x + gv.x * (bf2f(u0.x) + bf2f(u1.x));
    v.y = xv.y + pb.y + gv.y * (bf2f(u0.y) + bf2f(u1.y));
    v.z = xv.z + pb.z + gv.z * (bf2f(u0.z) + bf2f(u1.z));
    v.w = xv.w + pb.w + gv.w * (bf2f(u0.w) + bf2f(u1.w));
    *(float4*)(x1 + base) = v;

    float s  = v.x + v.y + v.z + v.w;
    float s2 = v.x * v.x + v.y * v.y + v.z * v.z + v.w * v.w;
#pragma unroll
    for (int o2 = 32; o2 > 0; o2 >>= 1) { s += __shfl_down(s, o2); s2 += __shfl_down(s2, o2); }
    __shared__ float sh[10];
    const int lane = tid & 63, wave = tid >> 6;
    if (lane == 0) { sh[wave] = s; sh[4 + wave] = s2; }
    __syncthreads();
    if (tid == 0) {
        float S1 = sh[0] + sh[1] + sh[2] + sh[3];
        float S2 = sh[4] + sh[5] + sh[6] + sh[7];
        float mean = S1 * (1.0f / Cv);
        float var  = S2 * (1.0f / Cv) - mean * mean;
        sh[8] = mean;
        sh[9] = rsqrtf(var + 1e-5f);
    }
    __syncthreads();
    const float mean = sh[8], rstd = sh[9];
    float4 wv = *(const float4*)(w + c);
    float4 bv = *(const float4*)(bvec + c);
    float o0 = (v.x - mean) * rstd * wv.x + bv.x;
    float o1 = (v.y - mean) * rstd * wv.y + bv.y;
    float o2 = (v.z - mean) * rstd * wv.z + bv.z;
    float o3 = (v.w - mean) * rstd * wv.w + bv.w;
    *(unsigned int*)(y8 + base) = f4_fp8(o0 * 16.f, o1 * 16.f, o2 * 16.f, o3 * 16.f);
}

// ---------------------------------------------------------------------------
// bf16 GEMM (128x128, BK=32, dbuf LDS, counted-vmcnt pipeline).
// MODE 0: bf16 out; MODE 1: gelu bf16; MODE 2: fp8(16*v) scattered into
// cat rows (r/Iv)*Sv + r%Iv (byte stride Cv) — ir2 + kv-scatter fusion.
// ---------------------------------------------------------------------------
template <int MODE>
__global__ __launch_bounds__(256) void gemm_bf16_kernel(
        const unsigned short* __restrict__ A,
        const unsigned short* __restrict__ W,
        const float* __restrict__ bias,
        unsigned short* __restrict__ outp,
        int M, int N, int K) {
    __shared__ unsigned short As[2][128 * 32];
    __shared__ unsigned short Bs[2][128 * 32];
    const int tid  = threadIdx.x;
    const int lane = tid & 63;
    const int wave = tid >> 6;
    const int m16  = lane & 15;
    const int g4   = lane >> 4;
    const int n0 = blockIdx.x * 128;
    const int m0 = blockIdx.y * 128;
    const int wm = (wave >> 1) * 64;
    const int wn = (wave & 1) * 64;

    const int r0  = tid >> 2;
    const int cc0 = (tid & 3) * 8;
    int am0 = m0 + r0;       if (am0 > M - 1) am0 = M - 1;
    int am1 = m0 + r0 + 64;  if (am1 > M - 1) am1 = M - 1;
    const unsigned short* agp0 = A + (size_t)am0 * K + cc0;
    const unsigned short* agp1 = A + (size_t)am1 * K + cc0;
    const unsigned short* bgp0 = W + (size_t)(n0 + r0) * K + cc0;
    const unsigned short* bgp1 = W + (size_t)(n0 + r0 + 64) * K + cc0;

    f32x4_t acc[4][4];
#pragma unroll
    for (int a = 0; a < 4; ++a)
#pragma unroll
        for (int bb = 0; bb < 4; ++bb) acc[a][bb] = zero4();

    auto stage = [&](int buf) {
        gload_lds16(agp0, &As[buf][wave * 512]);
        gload_lds16(agp1, &As[buf][2048 + wave * 512]);
        gload_lds16(bgp0, &Bs[buf][wave * 512]);
        gload_lds16(bgp1, &Bs[buf][2048 + wave * 512]);
        agp0 += 32; agp1 += 32; bgp0 += 32; bgp1 += 32;
    };

    auto body = [&](int cur) {
        bf16x8_t xf[4], wf[4];
#pragma unroll
        for (int bb = 0; bb < 4; ++bb)
            xf[bb] = *(const bf16x8_t*)&As[cur][(wm + bb * 16 + m16) * 32 + g4 * 8];
#pragma unroll
        for (int a = 0; a < 4; ++a)
            wf[a] = *(const bf16x8_t*)&Bs[cur][(wn + a * 16 + m16) * 32 + g4 * 8];
#pragma unroll
        for (int a = 0; a < 4; ++a)
#pragma unroll
            for (int bb = 0; bb < 4; ++bb)
                acc[a][bb] = __builtin_amdgcn_mfma_f32_16x16x32_bf16(wf[a], xf[bb], acc[a][bb], 0, 0, 0);
    };

    const int NIT = K >> 5;
    stage(0);
    stage(1);
    for (int it = 0; it < NIT - 1; ++it) {
        const int cur = it & 1;
        PIPE_WAIT(4);
        body(cur);
        PIPE_RELEASE();
        if (it + 2 < NIT) stage(cur);
    }
    PIPE_WAIT(0);
    body((NIT - 1) & 1);

#pragma unroll
    for (int a = 0; a < 4; ++a) {
        const int cb = n0 + wn + a * 16 + g4 * 4;
        const float4 bv4 = *(const float4*)(bias + cb);
#pragma unroll
        for (int bb = 0; bb < 4; ++bb) {
            const int r = m0 + wm + bb * 16 + m16;
            if (r < M) {
                const float v0 = acc[a][bb][0] + bv4.x;
                const float v1 = acc[a][bb][1] + bv4.y;
                const float v2 = acc[a][bb][2] + bv4.z;
                const float v3 = acc[a][bb][3] + bv4.w;
                if constexpr (MODE == 0) {
                    const size_t idx = (size_t)r * N + cb;
                    ushort4 o = {f2bf(v0), f2bf(v1), f2bf(v2), f2bf(v3)};
                    *(ushort4*)(outp + idx) = o;
                } else if constexpr (MODE == 1) {
                    const size_t idx = (size_t)r * N + cb;
                    ushort4 o = {f2bf(gelu_f(v0)), f2bf(gelu_f(v1)),
                                 f2bf(gelu_f(v2)), f2bf(gelu_f(v3))};
                    *(ushort4*)(outp + idx) = o;
                } else {
                    const int rr2 = (r / Iv) * Sv + (r % Iv);
                    *(unsigned int*)((unsigned char*)outp + (size_t)rr2 * Cv + cb) =
                        f4_fp8(v0 * 16.f, v1 * 16.f, v2 * 16.f, v3 * 16.f);
                }
            }
        }
    }
}

// ---------------------------------------------------------------------------
// MX-fp8 GEMM (unit scales) -> bf16 out + bias. BK=128, XOR slot-swizzled
// dual-LDS, compiler-drain mainloop (r4/r5 proven fastest; A-direct variant
// regressed -39% in r7 — blocking per-iter L2 loads beat occupancy gain).
// M-clamped staging + guarded stores (qkv: M=4404).
// ---------------------------------------------------------------------------
__global__ __launch_bounds__(256) void gemm_fp8_bf16out_kernel(
        const unsigned char* __restrict__ A,
        const unsigned char* __restrict__ W,
        const float* __restrict__ bias,
        unsigned short* __restrict__ outp,
        int M, int N, int K) {
    __shared__ unsigned char As[2][128 * 128];
    __shared__ unsigned char Bs[2][128 * 128];
    const int tid  = threadIdx.x;
    const int lane = tid & 63;
    const int wave = tid >> 6;
    const int m16  = lane & 15;
    const int g4   = lane >> 4;
    const int n0 = blockIdx.x * 128;
    const int m0 = blockIdx.y * 128;
    const int wm = (wave >> 1) * 64;
    const int wn = (wave & 1) * 64;

    const int rowin = tid >> 3;                       // 0..31
    const int sslot = (tid & 7) ^ (rowin & 7);
    const unsigned char* agp[4];
#pragma unroll
    for (int j = 0; j < 4; ++j) {
        int gr = m0 + j * 32 + rowin; if (gr > M - 1) gr = M - 1;
        agp[j] = A + (size_t)gr * K + sslot * 16;
    }
    const unsigned char* bgp = W + (size_t)(n0 + rowin) * K + sslot * 16;

    const int sw = m16 & 7;
    const int ra0 = ((2 * g4) ^ sw) * 16;
    const int ra1 = ((2 * g4 + 1) ^ sw) * 16;

    f32x4_t acc[4][4];
#pragma unroll
    for (int a = 0; a < 4; ++a)
#pragma unroll
        for (int bb = 0; bb < 4; ++bb) acc[a][bb] = zero4();

    auto stage = [&](int buf) {
#pragma unroll
        for (int j = 0; j < 4; ++j) {
            gload_lds16(agp[j], &As[buf][j * 4096 + wave * 1024]);
            gload_lds16(bgp + (size_t)j * 32 * K, &Bs[buf][j * 4096 + wave * 1024]);
            agp[j] += 128;
        }
        bgp += 128;
    };

    stage(0);
    const int NIT = K >> 7;
    for (int it = 0; it < NIT; ++it) {
        const int cur = it & 1;
        __syncthreads();
        if (it + 1 < NIT) stage(cur ^ 1);
        i32x8_t xv[4], wv[4];
#pragma unroll
        for (int bb = 0; bb < 4; ++bb) {
            const unsigned char* rb = &As[cur][(wm + bb * 16 + m16) * 128];
            xv[bb] = frag32(rb + ra0, rb + ra1);
        }
#pragma unroll
        for (int a = 0; a < 4; ++a) {
            const unsigned char* rb = &Bs[cur][(wn + a * 16 + m16) * 128];
            wv[a] = frag32(rb + ra0, rb + ra1);
        }
#pragma unroll
        for (int a = 0; a < 4; ++a)
#pragma unroll
            for (int bb = 0; bb < 4; ++bb)
                acc[a][bb] = __builtin_amdgcn_mfma_scale_f32_16x16x128_f8f6f4(
                    wv[a], xv[bb], acc[a][bb], 0, 0, 0, 0x7f7f7f7f, 0, 0x7f7f7f7f);
    }

    const float ds = 1.0f / 512.0f;
#pragma unroll
    for (int a = 0; a < 4; ++a) {
        const int cb = n0 + wn + a * 16 + g4 * 4;
        const float4 bv4 = *(const float4*)(bias + cb);
#pragma unroll
        for (int bb = 0; bb < 4; ++bb) {
            const int r = m0 + wm + bb * 16 + m16;
            if (r < M) {
                const size_t idx = (size_t)r * N + cb;
                ushort4 o = {f2bf(acc[a][bb][0] * ds + bv4.x),
                             f2bf(acc[a][bb][1] * ds + bv4.y),
                             f2bf(acc[a][bb][2] * ds + bv4.z),
                             f2bf(acc[a][bb][3] * ds + bv4.w)};
                *(ushort4*)(outp + idx) = o;
            }
        }
    }
}

// ---------------------------------------------------------------------------
// MX-fp8 GEMM, BK=128, fused gelu epilogue (fc1+pfc1). Dual-LDS drain
// mainloop (r4/r5 proven). out fp8 = fp8( 16 * gelu(acc/512 + bias) ).
// ---------------------------------------------------------------------------
__global__ __launch_bounds__(256) void gemm_fp8_gelu_kernel(
        const unsigned char* __restrict__ A,
        const unsigned char* __restrict__ W,
        const float* __restrict__ bias,
        unsigned char* __restrict__ outp,
        int M, int N, int K) {
    __shared__ unsigned char As[2][128 * 128];
    __shared__ unsigned char Bs[2][128 * 128];
    const int tid  = threadIdx.x;
    const int lane = tid & 63;
    const int wave = tid >> 6;
    const int m16  = lane & 15;
    const int g4   = lane >> 4;
    const int bid = blockIdx.x;
    const int xcd = bid & 7, l = bid >> 3;
    const int by = (xcd << 2) | (l & 3);   // m-tile (32)
    const int bx = l >> 2;                 // n-tile (64)
    const int n0 = bx * 128;
    const int m0 = by * 128;
    const int wm = (wave >> 1) * 64;
    const int wn = (wave & 1) * 64;

    const int rowin = tid >> 3;                       // 0..31
    const int sslot = (tid & 7) ^ (rowin & 7);
    const unsigned char* agp = A + (size_t)(m0 + rowin) * K + sslot * 16;
    const unsigned char* bgp = W + (size_t)(n0 + rowin) * K + sslot * 16;

    const int sw = m16 & 7;
    const int ra0 = ((2 * g4) ^ sw) * 16;
    const int ra1 = ((2 * g4 + 1) ^ sw) * 16;

    f32x4_t acc[4][4];
#pragma unroll
    for (int a = 0; a < 4; ++a)
#pragma unroll
        for (int bb = 0; bb < 4; ++bb) acc[a][bb] = zero4();

    auto stage = [&](int buf) {
#pragma unroll
        for (int j = 0; j < 4; ++j) {
            gload_lds16(agp + (size_t)j * 32 * K, &As[buf][j * 4096 + wave * 1024]);
            gload_lds16(bgp + (size_t)j * 32 * K, &Bs[buf][j * 4096 + wave * 1024]);
        }
        agp += 128; bgp += 128;
    };

    stage(0);
    const int NIT = K >> 7;
    for (int it = 0; it < NIT; ++it) {
        const int cur = it & 1;
        __syncthreads();
        if (it + 1 < NIT) stage(cur ^ 1);
        i32x8_t xv[4], wv[4];
#pragma unroll
        for (int bb = 0; bb < 4; ++bb) {
            const unsigned char* rb = &As[cur][(wm + bb * 16 + m16) * 128];
            xv[bb] = frag32(rb + ra0, rb + ra1);
        }
#pragma unroll
        for (int a = 0; a < 4; ++a) {
            const unsigned char* rb = &Bs[cur][(wn + a * 16 + m16) * 128];
            wv[a] = frag32(rb + ra0, rb + ra1);
        }
#pragma unroll
        for (int a = 0; a < 4; ++a)
#pragma unroll
            for (int bb = 0; bb < 4; ++bb)
                acc[a][bb] = __builtin_amdgcn_mfma_scale_f32_16x16x128_f8f6f4(
                    wv[a], xv[bb], acc[a][bb], 0, 0, 0, 0x7f7f7f7f, 0, 0x7f7f7f7f);
    }

    const float ds = 1.0f / 512.0f;
#pragma unroll
    for (int a = 0; a < 4; ++a) {
        const int cb = n0 + wn + a * 16 + g4 * 4;
        const float4 bv4 = *(const float4*)(bias + cb);
#pragma unroll
        for (int bb = 0; bb < 4; ++bb) {
            const int r = m0 + wm + bb * 16 + m16;
            const size_t idx = (size_t)r * N + cb;
            unsigned int pk = f4_fp8(gelu_f(acc[a][bb][0] * ds + bv4.x) * 16.f,
                                     gelu_f(acc[a][bb][1] * ds + bv4.y) * 16.f,
                                     gelu_f(acc[a][bb][2] * ds + bv4.z) * 16.f,
                                     gelu_f(acc[a][bb][3] * ds + bv4.w) * 16.f);
            *(unsigned int*)(outp + idx) = pk;
        }
    }
}

// ---------------------------------------------------------------------------
// MX-fp8 split-K GEMM -> bf16 partials (acc/512). XCD-swizzled 1D grid (512).
// z<zsplit -> (A1,W1) else (A2,W2); k0=(z%zsplit)*Kc. Drain mainloop.
// ---------------------------------------------------------------------------
__global__ __launch_bounds__(256) void gemm_fp8_splitk_kernel(
        const unsigned char* __restrict__ A1,
        const unsigned char* __restrict__ W1,
        const unsigned char* __restrict__ A2,
        const unsigned char* __restrict__ W2,
        unsigned short* __restrict__ parts,
        int M, int N, int lda, int ldw, int Kc, int zsplit) {
    __shared__ unsigned char As[2][128 * 128];
    __shared__ unsigned char Bs[2][128 * 128];
    const int tid  = threadIdx.x;
    const int lane = tid & 63;
    const int wave = tid >> 6;
    const int m16  = lane & 15;
    const int g4   = lane >> 4;
    const int bid = blockIdx.x;
    const int xcd = bid & 7, l = bid >> 3;
    const int by = (xcd << 2) | (l & 3);
    const int rr = l >> 2;
    const int bx = rr & 7;
    const int z  = rr >> 3;
    const int n0 = bx * 128;
    const int m0 = by * 128;
    const int wm = (wave >> 1) * 64;
    const int wn = (wave & 1) * 64;

    const unsigned char* A = (z < zsplit) ? A1 : A2;
    const unsigned char* W = (z < zsplit) ? W1 : W2;
    const int k0 = (z % zsplit) * Kc;

    const int rowin = tid >> 3;
    const int sslot = (tid & 7) ^ (rowin & 7);
    const unsigned char* agp = A + (size_t)(m0 + rowin) * lda + k0 + sslot * 16;
    const unsigned char* bgp = W + (size_t)(n0 + rowin) * ldw + k0 + sslot * 16;

    const int sw = m16 & 7;
    const int ra0 = ((2 * g4) ^ sw) * 16;
    const int ra1 = ((2 * g4 + 1) ^ sw) * 16;

    f32x4_t acc[4][4];
#pragma unroll
    for (int a = 0; a < 4; ++a)
#pragma unroll
        for (int bb = 0; bb < 4; ++bb) acc[a][bb] = zero4();

    auto stage = [&](int buf) {
#pragma unroll
        for (int j = 0; j < 4; ++j) {
            gload_lds16(agp + (size_t)j * 32 * lda, &As[buf][j * 4096 + wave * 1024]);
            gload_lds16(bgp + (size_t)j * 32 * ldw, &Bs[buf][j * 4096 + wave * 1024]);
        }
        agp += 128; bgp += 128;
    };

    stage(0);
    const int NIT = Kc >> 7;
    for (int it = 0; it < NIT; ++it) {
        const int cur = it & 1;
        __syncthreads();
        if (it + 1 < NIT) stage(cur ^ 1);
        i32x8_t xv[4], wv[4];
#pragma unroll
        for (int bb = 0; bb < 4; ++bb) {
            const unsigned char* rb = &As[cur][(wm + bb * 16 + m16) * 128];
            xv[bb] = frag32(rb + ra0, rb + ra1);
        }
#pragma unroll
        for (int a = 0; a < 4; ++a) {
            const unsigned char* rb = &Bs[cur][(wn + a * 16 + m16) * 128];
            wv[a] = frag32(rb + ra0, rb + ra1);
        }
#pragma unroll
        for (int a = 0; a < 4; ++a)
#pragma unroll
            for (int bb = 0; bb < 4; ++bb)
                acc[a][bb] = __builtin_amdgcn_mfma_scale_f32_16x16x128_f8f6f4(
                    wv[a], xv[bb], acc[a][bb], 0, 0, 0, 0x7f7f7f7f, 0, 0x7f7f7f7f);
    }

    unsigned short* pz = parts + (size_t)z * M * N;
    const float ds = 1.0f / 512.0f;
#pragma unroll
    for (int a = 0; a < 4; ++a) {
        const int cb = n0 + wn + a * 16 + g4 * 4;
#pragma unroll
        for (int bb = 0; bb < 4; ++bb) {
            const int r = m0 + wm + bb * 16 + m16;
            const size_t idx = (size_t)r * N + cb;
            ushort4 o = {f2bf(acc[a][bb][0] * ds), f2bf(acc[a][bb][1] * ds),
                         f2bf(acc[a][bb][2] * ds), f2bf(acc[a][bb][3] * ds)};
            *(ushort4*)(pz + idx) = o;
        }
    }
}

// ---------------------------------------------------------------------------
// Split-K reduce: out[i] = resid[i] + bias[i%N] + sum_z parts[z][i]  (fp32 out)
// ---------------------------------------------------------------------------
template <int NP>
__global__ __launch_bounds__(256) void reduce_kernel(
        const unsigned short* __restrict__ parts,
        const float* __restrict__ resid,
        const float* __restrict__ bias,
        float* __restrict__ out, int MN, int N4mask) {
    int i = blockIdx.x * 256 + threadIdx.x;
    if (i * 4 >= MN) return;
    float4 res = ((const float4*)resid)[i];
    float4 bv  = *(const float4*)(bias + (i & N4mask) * 4);
    float4 o = {res.x + bv.x, res.y + bv.y, res.z + bv.z, res.w + bv.w};
#pragma unroll
    for (int z = 0; z < NP; ++z) {
        ushort4 u = ((const ushort4*)(parts + (size_t)z * MN))[i];
        o.x += bf2f(u.x); o.y += bf2f(u.y); o.z += bf2f(u.z); o.w += bf2f(u.w);
    }
    ((float4*)out)[i] = o;
}

// ---------------------------------------------------------------------------
// V^T pre-transpose with baked PV key-permutation.
// ---------------------------------------------------------------------------
__global__ __launch_bounds__(256) void vtrans_kernel(const unsigned short* __restrict__ qkv,
                                                     unsigned short* __restrict__ vt) {
    __shared__ unsigned short Vs[64 * 64];
    const int stile = blockIdx.x;
    const int bh = blockIdx.y;
    const int b = bh >> 4, h = bh & 15;
    const int tid = threadIdx.x;
#pragma unroll
    for (int j = 0; j < 2; ++j) {
        int c = j * 256 + tid;
        int r = c >> 3, d8 = (c & 7) * 8;
        int s = stile * 64 + r;
        uint4 v = {0u, 0u, 0u, 0u};
        if (s < Sv) v = *(const uint4*)(qkv + ((size_t)(b * Sv + s) * 3 + 2) * Cv + h * 64 + d8);
        *(uint4*)&Vs[r * 64 + d8] = v;
    }
    __syncthreads();
    const int d  = tid >> 2;
    const int p0 = (tid & 3) * 16;
    unsigned short tmp[16];
#pragma unroll
    for (int e = 0; e < 16; ++e) {
        int p = p0 + e;
        int s_local = (p & 32) + 16 * ((p >> 2) & 1) + 4 * ((p & 31) >> 3) + (p & 3);
        tmp[e] = Vs[s_local * 64 + d];
    }
    unsigned short* dst = vt + ((size_t)bh * 64 + d) * SPADv + stile * 64 + p0;
    *(uint4*)dst       = *(const uint4*)&tmp[0];
    *(uint4*)(dst + 8) = *(const uint4*)&tmp[8];
}

// ---------------------------------------------------------------------------
// Flash attention, S^T formulation, 128 q-rows/block (32/wave, 2 groups).
// K/V staged per 64-key tile serve 2x the q-rows vs the 64-row version:
// staging traffic, barriers, and block count all halve. Q fragments load
// DIRECT from global in natural k-order (the LDS store/read XORs cancel:
// LDS[row][slot] = global[row][slot^(row&7)], read XORs sw7=row&7).
// Output -> fp8(16*o) for fp8 proj.
// ---------------------------------------------------------------------------
__global__ __launch_bounds__(256) void attn_kernel(const unsigned short* __restrict__ qkv,
                                                   const unsigned short* __restrict__ vt,
                                                   unsigned char* __restrict__ o) {
    __shared__ unsigned short Ks[2][64 * 64];
    __shared__ unsigned short Vts[2][64 * 64];

    const int tid  = threadIdx.x;
    const int lane = tid & 63;
    const int wave = tid >> 6;
    const int m16  = lane & 15;
    const int g4   = lane >> 4;
    const int qt = blockIdx.x;
    const int bh = blockIdx.y;
    const int b = bh >> 4, h = bh & 15;

    const int lr = lane >> 3;
    const int csw = ((lane & 7) ^ lr) * 8;
    const int sw7 = m16 & 7;

    // Q fragments: rows qt*128 + wave*32 + g*16 + m16, direct global loads
    bf16x8_t qf0[2], qf1[2];
#pragma unroll
    for (int g = 0; g < 2; ++g) {
        const int s = Iv + qt * 128 + wave * 32 + g * 16 + m16;
        const unsigned short* qp = qkv + ((size_t)(b * Sv + s) * 3) * Cv + h * 64 + g4 * 8;
        qf0[g] = *(const bf16x8_t*)qp;
        qf1[g] = *(const bf16x8_t*)(qp + 32);
    }

    auto stage_kv = [&](int st, int buf) {
#pragma unroll
        for (int j = 0; j < 2; ++j) {
            int r = wave * 16 + j * 8 + lr;
            int s = st * 64 + r; if (s > Sv - 1) s = Sv - 1;
            gload_lds16(qkv + ((size_t)(b * Sv + s) * 3 + 1) * Cv + h * 64 + csw,
                        &Ks[buf][(wave * 16 + j * 8) * 64]);
            gload_lds16(vt + ((size_t)bh * 64 + r) * SPADv + st * 64 + csw,
                        &Vts[buf][(wave * 16 + j * 8) * 64]);
        }
    };

    f32x4_t oaccA[4], oaccB[4];
#pragma unroll
    for (int dt = 0; dt < 4; ++dt) { oaccA[dt] = zero4(); oaccB[dt] = zero4(); }
    float m_runA = -1e30f, l_runA = 0.f;
    float m_runB = -1e30f, l_runB = 0.f;

    stage_kv(0, 0);
    __syncthreads();

    const int NT = (Sv + 63) / 64;   // 18
    for (int st = 0; st < NT; ++st) {
        const int cur = st & 1;
        if (st + 1 < NT) stage_kv(st + 1, cur ^ 1);

        // K fragments shared by both q-groups
        bf16x8_t k0[4], k1[4];
#pragma unroll
        for (int kt = 0; kt < 4; ++kt) {
            k0[kt] = *(const bf16x8_t*)&Ks[cur][(kt * 16 + m16) * 64 + ((g4 ^ sw7) * 8)];
            k1[kt] = *(const bf16x8_t*)&Ks[cur][(kt * 16 + m16) * 64 + (((4 + g4) ^ sw7) * 8)];
        }
        bf16x8_t v0[4], v1[4];
#pragma unroll
        for (int dt = 0; dt < 4; ++dt) {
            v0[dt] = *(const bf16x8_t*)&Vts[cur][(dt * 16 + m16) * 64 + ((g4 ^ sw7) * 8)];
            v1[dt] = *(const bf16x8_t*)&Vts[cur][(dt * 16 + m16) * 64 + (((4 + g4) ^ sw7) * 8)];
        }

#pragma unroll
        for (int g = 0; g < 2; ++g) {
            const bf16x8_t qa = g ? qf0[1] : qf0[0];
            const bf16x8_t qb = g ? qf1[1] : qf1[0];
            f32x4_t* oacc = g ? oaccB : oaccA;
            float m_run = g ? m_runB : m_runA;
            float l_run = g ? l_runB : l_runA;

            f32x4_t sc[4];
#pragma unroll
            for (int kt = 0; kt < 4; ++kt) {
                f32x4_t z = zero4();
                z = __builtin_amdgcn_mfma_f32_16x16x32_bf16(k0[kt], qa, z, 0, 0, 0);
                z = __builtin_amdgcn_mfma_f32_16x16x32_bf16(k1[kt], qb, z, 0, 0, 0);
                sc[kt] = z;
            }

            float mx = -1e30f;
#pragma unroll
            for (int kt = 0; kt < 4; ++kt)
#pragma unroll
                for (int r = 0; r < 4; ++r) {
                    int key = st * 64 + kt * 16 + g4 * 4 + r;
                    float v = sc[kt][r] * 0.125f;
                    v = (key < Sv) ? v : -1e30f;
                    sc[kt][r] = v;
                    mx = fmaxf(mx, v);
                }
            mx = fmaxf(mx, __shfl_xor(mx, 16));
            mx = fmaxf(mx, __shfl_xor(mx, 32));
            const float mnew  = fmaxf(m_run, mx);
            const float alpha = __expf(m_run - mnew);
            m_run = mnew;
            float sum = 0.f;
#pragma unroll
            for (int kt = 0; kt < 4; ++kt)
#pragma unroll
                for (int r = 0; r < 4; ++r) {
                    float p = __expf(sc[kt][r] - mnew);
                    sc[kt][r] = p;
                    sum += p;
                }
            sum += __shfl_xor(sum, 16);
            sum += __shfl_xor(sum, 32);
            l_run = l_run * alpha + sum;
#pragma unroll
            for (int dt = 0; dt < 4; ++dt) oacc[dt] *= alpha;

            us8_t pu0, pu1;
#pragma unroll
            for (int j = 0; j < 8; ++j) {
                pu0[j] = f2bf(sc[(j >> 2)][j & 3]);
                pu1[j] = f2bf(sc[2 + (j >> 2)][j & 3]);
            }
            const bf16x8_t pf0 = __builtin_bit_cast(bf16x8_t, pu0);
            const bf16x8_t pf1 = __builtin_bit_cast(bf16x8_t, pu1);

#pragma unroll
            for (int dt = 0; dt < 4; ++dt) {
                oacc[dt] = __builtin_amdgcn_mfma_f32_16x16x32_bf16(v0[dt], pf0, oacc[dt], 0, 0, 0);
                oacc[dt] = __builtin_amdgcn_mfma_f32_16x16x32_bf16(v1[dt], pf1, oacc[dt], 0, 0, 0);
            }
            if (g) { m_runB = m_run; l_runB = l_run; }
            else   { m_runA = m_run; l_runA = l_run; }
        }
        __syncthreads();
    }

#pragma unroll
    for (int g = 0; g < 2; ++g) {
        const f32x4_t* oacc = g ? oaccB : oaccA;
        const float inv16 = 16.0f / (g ? l_runB : l_runA);
        const int q = qt * 128 + wave * 32 + g * 16 + m16;
        const size_t row = (size_t)(b * Nv + q) * Cv + h * 64;
#pragma unroll
        for (int dt = 0; dt < 4; ++dt) {
            *(unsigned int*)&o[row + dt * 16 + g4 * 4] =
                f4_fp8(oacc[dt][0] * inv16, oacc[dt][1] * inv16,
                       oacc[dt][2] * inv16, oacc[dt][3] * inv16);
        }
    }
}

// ---------------------------------------------------------------------------
// Launcher
// ---------------------------------------------------------------------------
extern "C" void kernel_launch(void* const* d_in, const int* in_sizes, int n_in,
                              void* d_out, int out_size, void* d_ws, size_t ws_size,
                              hipStream_t stream) {
    (void)in_sizes; (void)n_in; (void)out_size; (void)ws_size;
    const float* x       = (const float*)d_in[0];
    const float* instr   = (const float*)d_in[1];
    const float* norm1_w = (const float*)d_in[2];
    const float* norm1_b = (const float*)d_in[3];
    const float* qkv_w   = (const float*)d_in[4];
    const float* q_bias  = (const float*)d_in[5];
    const float* v_bias  = (const float*)d_in[6];
    const float* proj_w  = (const float*)d_in[7];
    const float* proj_b  = (const float*)d_in[8];
    const float* gamma_1 = (const float*)d_in[9];
    const float* gamma_2 = (const float*)d_in[10];
    const float* norm2_w = (const float*)d_in[11];
    const float* norm2_b = (const float*)d_in[12];
    const float* fc1_w   = (const float*)d_in[13];
    const float* fc1_b   = (const float*)d_in[14];
    const float* fc2_w   = (const float*)d_in[15];
    const float* fc2_b   = (const float*)d_in[16];
    const float* pfc1_w  = (const float*)d_in[17];
    const float* pfc1_b  = (const float*)d_in[18];
    const float* pfc2_w  = (const float*)d_in[19];
    const float* pfc2_b  = (const float*)d_in[20];
    const float* gate    = (const float*)d_in[21];
    const float* ir_ln_w = (const float*)d_in[22];
    const float* ir_ln_b = (const float*)d_in[23];
    const float* ir_l1_w = (const float*)d_in[24];
    const float* ir_l1_b = (const float*)d_in[25];
    const float* ir_l2_w = (const float*)d_in[26];
    const float* ir_l2_b = (const float*)d_in[27];
    float* out = (float*)d_out;

    char* ws = (char*)d_ws;
    size_t off = 0;
    auto alloc = [&](size_t bytes) -> char* {
        char* p = ws + off;
        off += (bytes + 255) & ~(size_t)255;
        return p;
    };
    unsigned char*  w_qkv8 = (unsigned char*)alloc((size_t)3 * Cv * Cv);       // fp8 x32
    unsigned char*  w_proj8= (unsigned char*)alloc((size_t)Cv * Cv);           // fp8 x32 (no g1)
    unsigned char*  w_mlp1 = (unsigned char*)alloc((size_t)2 * HIDv * Cv);     // fp8: fc1|pfc1 x32
    unsigned char*  w_fc2  = (unsigned char*)alloc((size_t)Cv * HIDv);         // fp8 *g2*32
    unsigned char*  w_pfc2 = (unsigned char*)alloc((size_t)Cv * HIDv);         // fp8 *gate*32
    unsigned short* w_ir1  = (unsigned short*)alloc((size_t)Cv * IDv * 2);
    unsigned short* w_ir2  = (unsigned short*)alloc((size_t)Cv * Cv * 2);
    float*          qkvb   = (float*)alloc((size_t)3 * Cv * 4);
    float*          bfuse  = (float*)alloc((size_t)Cv * 4);
    float*          projb  = (float*)alloc((size_t)Cv * 4);
    float*          bcat   = (float*)alloc((size_t)2 * HIDv * 4);
    unsigned short* irln   = (unsigned short*)alloc((size_t)BIv * IDv * 2);
    unsigned short* h1     = (unsigned short*)alloc((size_t)BIv * Cv * 2);
    unsigned char*  cat8   = (unsigned char*)alloc((size_t)BSv * Cv);          // fp8 x16, 4.5 MB
    unsigned short* qkvbuf = (unsigned short*)alloc((size_t)BSv * 3 * Cv * 2); // bf16 27.1 MB
    unsigned char*  obuf8  = (unsigned char*)alloc((size_t)BNv * Cv);          // fp8 x16
    float*          x1     = (float*)alloc((size_t)BNv * Cv * 4);
    unsigned char*  ybuf8  = (unsigned char*)alloc((size_t)BNv * Cv);          // fp8 x16
    unsigned char*  gbufA  = (unsigned char*)alloc((size_t)BNv * 2 * HIDv);    // fp8 33.6 MB
    unsigned short* fpart  = (unsigned short*)alloc((size_t)2 * BNv * Cv * 2); // 16.8 MB (2 partials)
    unsigned short* vt     = (unsigned short*)gbufA;  // vt dead before fc1 writes gbufA
    unsigned short* ppart  = fpart;                   // fpart free until fc2 splitk

    cvt8_kernel<<<22272, 256, 0, stream>>>(qkv_w, proj_w, fc1_w, fc2_w, pfc1_w, pfc2_w,
                                           ir_l1_w, ir_l2_w,
                                           w_qkv8, w_proj8, w_mlp1, w_fc2,
                                           w_mlp1 + (size_t)HIDv * Cv, w_pfc2,
                                           w_ir1, w_ir2,
                                           gamma_1, gamma_2, gate);

    bias_prep_kernel<<<52, 256, 0, stream>>>(q_bias, v_bias, fc2_b, pfc2_b, proj_b,
                                             fc1_b, pfc1_b,
                                             gamma_1, gamma_2, gate,
                                             qkvb, bfuse, projb, bcat);

    // instruct branch: LN -> Linear+GELU -> Linear (epilogue scatters fp8 into cat)
    ln_kernel<0><<<BIv, 256, 0, stream>>>(instr, ir_ln_w, ir_ln_b, irln,
                                          IDv, 1.0f / IDv, 1 << 28, 0, 0);
    // LN1 writes fp8(16*y) directly into cat rows b*S + I + n
    ln_kernel<1><<<BNv, 256, 0, stream>>>(x, norm1_w, norm1_b, cat8,
                                          Cv, 1.0f / Cv, Nv, Sv, Iv);
    gemm_bf16_kernel<1><<<dim3(Cv / 128, (BIv + 127) / 128), 256, 0, stream>>>(
        irln, w_ir1, ir_l1_b, h1, BIv, Cv, IDv);
    gemm_bf16_kernel<2><<<dim3(Cv / 128, (BIv + 127) / 128), 256, 0, stream>>>(
        h1, w_ir2, ir_l2_b, (unsigned short*)cat8, BIv, Cv, Cv);

    // QKV projection over cat [BS, C] fp8 -> [BS, 3C] bf16 (MX-fp8 dual-LDS)
    gemm_fp8_bf16out_kernel<<<dim3(3 * Cv / 128, (BSv + 127) / 128), 256, 0, stream>>>(
        cat8, w_qkv8, qkvb, qkvbuf, BSv, 3 * Cv, Cv);

    // V^T pre-transpose (permuted), then attention (128 q-rows/block)
    vtrans_kernel<<<dim3(18, Bv * Hv), 256, 0, stream>>>(qkvbuf, vt);
    attn_kernel<<<dim3(Nv / 128, Bv * Hv), 256, 0, stream>>>(qkvbuf, vt, obuf8);

    // proj MX-fp8 split-K=2 (Kc=512, NIT=4, 512 blocks = one full round)
    gemm_fp8_splitk_kernel<<<512, 256, 0, stream>>>(
        obuf8, w_proj8, obuf8, w_proj8, ppart,
        BNv, Cv, Cv, Cv, Cv / 2, 2);
    // fused: x1 = x + g1*proj_b + g1*sum(parts); LN2 -> fp8(16*y)
    proj_ln2_kernel<<<BNv, 256, 0, stream>>>(
        ppart, x, projb, gamma_1, norm2_w, norm2_b, x1, ybuf8);

    // fused fc1+pfc1 (MX-fp8 dual-LDS, N=8192, XCD-swizzled 2048 blocks)
    gemm_fp8_gelu_kernel<<<2048, 256, 0, stream>>>(
        ybuf8, w_mlp1, bcat, gbufA, BNv, 2 * HIDv, Cv);

    // fc2 + pfc2 MX-fp8 split-K: z=0 -> fc2 (full K=4096), z=1 -> pfc2
    gemm_fp8_splitk_kernel<<<512, 256, 0, stream>>>(
        gbufA, w_fc2, gbufA + HIDv, w_pfc2, fpart,
        BNv, Cv, 2 * HIDv, HIDv, HIDv, 1);
    // out = x1 + (g2*fc2_b + gate*pfc2_b) + sum(parts)
    reduce_kernel<2><<<(BNv * Cv / 4 + 255) / 256, 256, 0, stream>>>(
        fpart, x1, bfuse, out, BNv * Cv, Cv / 4 - 1);
}